// Round 11
// baseline (196.066 us; speedup 1.0000x reference)
//
#include <hip/hip_runtime.h>

#define NN 50000
#define NE 800000

typedef unsigned short ushort_t;
typedef __attribute__((ext_vector_type(8))) short short8;
typedef __attribute__((ext_vector_type(4))) float f32x4;

constexpr int NB   = (NN + 127) / 128;                        // 391 dst-buckets (128 nodes)
constexpr int BCAP = 4096;                                    // bucket capacity (avg 2048)
constexpr int CH     = 4096;                                  // edges per phase-A block
constexpr int NBLK_E = (NE + CH - 1) / CH;                    // 196
constexpr int NBLK_M = (NN + 63) / 64;                        // 782 GEMM row-blocks
constexpr int NY4    = NN * 64 / 4;                           // 800000 float4 groups of y

// ---------------- bf16 helpers (bit-exact, RNE) ----------------
__device__ __forceinline__ float bf2f(ushort_t u) {
    union { unsigned int i; float f; } v;
    v.i = ((unsigned int)u) << 16;
    return v.f;
}
__device__ __forceinline__ float bf2f_u(unsigned int lo16) {  // low 16 bits hold bf16
    union { unsigned int i; float f; } v;
    v.i = lo16 << 16;
    return v.f;
}
__device__ __forceinline__ float hi16_as_f(unsigned int u) {  // high 16 bits hold bf16
    union { unsigned int i; float f; } v;
    v.i = u & 0xffff0000u;
    return v.f;
}
__device__ __forceinline__ ushort_t f2bf(float f) {
    union { float f; unsigned int u; } v;
    v.f = f;
    unsigned int r = (v.u + 0x7fffu + ((v.u >> 16) & 1u)) >> 16;
    return (ushort_t)r;
}

// ---------------- fused conversions (y -> bf16, W1^T, W2^T) ----------------

__global__ void cvt_all_k(const float* __restrict__ y, const float* __restrict__ W1,
                          const float* __restrict__ W2, ushort_t* __restrict__ ybf,
                          ushort_t* __restrict__ w1t, ushort_t* __restrict__ w2t) {
    int i = blockIdx.x * blockDim.x + threadIdx.x;
    if (i < NY4) {
        float4 v = reinterpret_cast<const float4*>(y)[i];
        ushort4 o;
        o.x = f2bf(v.x); o.y = f2bf(v.y); o.z = f2bf(v.z); o.w = f2bf(v.w);
        reinterpret_cast<ushort4*>(ybf)[i] = o;
    } else if (i < NY4 + 128 * 64) {
        int j = i - NY4;                  // w1t[c][k] = bf(W1[k][c]), W1 is [64][128]
        int c = j >> 6, k = j & 63;
        w1t[j] = f2bf(W1[k * 128 + c]);
    } else if (i < NY4 + 128 * 64 + 256 * 128) {
        int j = i - NY4 - 128 * 64;       // w2t[c][k] = bf(W2[k][c]), W2 is [128][256]
        int c = j >> 7, k = j & 127;
        w2t[j] = f2bf(W2[k * 256 + c]);
    }
}

// ---------------- CSR reorder, atomic-free at global scope ----------------

__global__ void bblk_k(const int* __restrict__ src, const int* __restrict__ dst,
                       const float* __restrict__ w, uint2* __restrict__ tmp,
                       int* __restrict__ cnt, int E) {
    __shared__ int lcnt[NB], lcur[NB];
    __shared__ uint2 rec[CH];
    int b = blockIdx.x, tid = threadIdx.x;
    int e0 = b * CH;
    int ec = min(CH, E - e0);
    for (int i = tid; i < NB; i += 256) lcnt[i] = 0;
    __syncthreads();
    for (int i = tid; i < ec; i += 256)
        atomicAdd(&lcnt[dst[e0 + i] >> 7], 1);
    __syncthreads();
    if (tid == 0) {
        int run = 0;
        for (int q = 0; q < NB; ++q) { lcur[q] = run; run += lcnt[q]; }
    }
    __syncthreads();
    for (int q = tid; q < NB; q += 256)
        cnt[q * NBLK_E + b] = (lcnt[q] << 16) | lcur[q];
    __syncthreads();
    for (int i = tid; i < ec; i += 256) {
        int d = dst[e0 + i];
        int p = atomicAdd(&lcur[d >> 7], 1);
        uint2 r;
        r.x = (unsigned int)src[e0 + i] | ((unsigned int)(d & 127) << 16);
        r.y = ((unsigned int)f2bf(w[e0 + i])) << 16;
        rec[p] = r;
    }
    __syncthreads();
    for (int i = tid; i < ec; i += 256)
        tmp[(size_t)e0 + i] = rec[i];
}

// per-bucket totals from cnt table (coalesced row reduce)
__global__ void bstat_k(const int* __restrict__ cnt, int* __restrict__ btot) {
    __shared__ int red[256];
    int q = blockIdx.x, tid = threadIdx.x;
    int s = (tid < NBLK_E) ? (cnt[q * NBLK_E + tid] >> 16) : 0;
    red[tid] = s;
    __syncthreads();
    for (int off = 128; off > 0; off >>= 1) {
        if (tid < off) red[tid] += red[tid + off];
        __syncthreads();
    }
    if (tid == 0) btot[q] = red[0];
}

// Phase B: one block per bucket — computes its own bucket start (prefix of btot),
// gathers the 196 runs, LDS counting-sort by dst&127, writes final CSR-ordered
// epack coalesced + per-node rp.
__global__ void bsort_k(const uint2* __restrict__ tmp, const int* __restrict__ cnt,
                        const int* __restrict__ btot, int* __restrict__ rp,
                        unsigned int* __restrict__ epack, int n) {
    __shared__ int rstart[NBLK_E + 1], rlofs[NBLK_E], rcnt[NBLK_E];
    __shared__ int c128[128], cur128[128], ex128[128];
    __shared__ int pre[256];
    __shared__ int s_start;
    __shared__ uint2 rec8[BCAP];
    __shared__ unsigned int spk[BCAP];
    int q = blockIdx.x, tid = threadIdx.x;
    int d0 = q * 128;
    {
        int part = 0;
        for (int b = tid; b < q; b += 256) part += btot[b];
        pre[tid] = part;
        __syncthreads();
        for (int off = 128; off > 0; off >>= 1) {
            if (tid < off) pre[tid] += pre[tid + off];
            __syncthreads();
        }
        if (tid == 0) {
            s_start = pre[0];
            if (q == 0) rp[n] = NE;
        }
        __syncthreads();
    }
    int start = s_start;
    for (int b = tid; b < NBLK_E; b += 256) {
        int v = cnt[q * NBLK_E + b];
        rcnt[b]  = v >> 16;
        rlofs[b] = v & 0xffff;
    }
    if (tid < 128) c128[tid] = 0;
    __syncthreads();
    if (tid == 0) {
        int run = 0;
        for (int b = 0; b < NBLK_E; ++b) { rstart[b] = run; run += rcnt[b]; }
        rstart[NBLK_E] = run;
    }
    __syncthreads();
    int total = min(rstart[NBLK_E], BCAP);
    for (int i = tid; i < total; i += 256) {
        int lo = 0, hi = NBLK_E;           // rstart[lo] <= i < rstart[hi]
        while (hi - lo > 1) {
            int mid = (lo + hi) >> 1;
            if (rstart[mid] <= i) lo = mid; else hi = mid;
        }
        uint2 r = tmp[(size_t)lo * CH + rlofs[lo] + (i - rstart[lo])];
        rec8[i] = r;
        atomicAdd(&c128[(r.x >> 16) & 127], 1);
    }
    __syncthreads();
    if (tid == 0) {
        int run = 0;
        for (int d = 0; d < 128; ++d) { ex128[d] = run; cur128[d] = run; run += c128[d]; }
    }
    __syncthreads();
    if (tid < 128 && d0 + tid < n) rp[d0 + tid] = start + ex128[tid];
    for (int i = tid; i < total; i += 256) {
        uint2 r = rec8[i];
        int p = atomicAdd(&cur128[(r.x >> 16) & 127], 1);
        spk[p] = r.y | (r.x & 0xffffu);
    }
    __syncthreads();
    for (int i = tid; i < total; i += 256)
        epack[start + i] = spk[i];
}

// ---------------- FUSED layer 1: spmm(ybf) -> LDS A-tile -> MFMA GEMM ----------------
// Block = 64 nodes. Phase 1: wave w gathers/accumulates nodes [w*16, w*16+16) of
// this block (lane = column, 8 edges in flight) and writes bf16 results straight
// into the XOR-swizzled LDS A-tile. Phase 2: identical to mgemm_k<64> (c0 = 0).
// Stats partials per block -> psum/psq (no global atomics).

__launch_bounds__(256, 4)
__global__ void fused1_k(const ushort_t* __restrict__ yb, const int* __restrict__ rp,
                         const unsigned int* __restrict__ ep,
                         const ushort_t* __restrict__ BT, ushort_t* __restrict__ h1,
                         float* __restrict__ psum, float* __restrict__ psq, int n) {
    constexpr int K = 64, K2 = 128;      // row bytes
    __shared__ char As[64 * K2];
    __shared__ float lsum[128], lsq[128];
    int tid  = threadIdx.x;
    int r0   = blockIdx.x * 64;
    int lane = tid & 63;
    int w    = tid >> 6;
    int wm0  = (w >> 1) * 32;
    int wn0  = (w & 1) * 64;
    int kg   = lane >> 4;
    int lr   = lane & 15;

    if (tid < 128) { lsum[tid] = 0.f; lsq[tid] = 0.f; }

    // B fragment preload (independent of the gather; hides under phase 1)
    short8 bfrag[2][4];
#pragma unroll
    for (int fn = 0; fn < 4; ++fn) {
        const ushort_t* bp = BT + (size_t)(wn0 + fn * 16 + lr) * K + kg * 8;
#pragma unroll
        for (int ks = 0; ks < 2; ++ks)
            bfrag[ks][fn] = *reinterpret_cast<const short8*>(bp + ks * 32);
    }

    // Phase 1: gather-spmm, 16 nodes per wave, straight into swizzled A-tile
#pragma unroll 1
    for (int nn = 0; nn < 16; ++nn) {
        int row  = w * 16 + nn;
        int node = r0 + row;
        float acc = 0.f;
        if (node < n) {
            int beg = rp[node], end = rp[node + 1];
            int p = beg;
            for (; p + 8 <= end; p += 8) {
                unsigned int m[8];
#pragma unroll
                for (int j = 0; j < 8; ++j) m[j] = ep[p + j];
                ushort_t u[8];
#pragma unroll
                for (int j = 0; j < 8; ++j)
                    u[j] = yb[(size_t)(m[j] & 0xffffu) * 64 + lane];
#pragma unroll
                for (int j = 0; j < 8; ++j)
                    acc = fmaf(hi16_as_f(m[j]), bf2f(u[j]), acc);
            }
            for (; p < end; ++p) {
                unsigned int m = ep[p];
                acc = fmaf(hi16_as_f(m), bf2f(yb[(size_t)(m & 0xffffu) * 64 + lane]), acc);
            }
        }
        int off  = lane * 2;
        int addr = row * K2 + (((off & 0x70) ^ ((row & 7) << 4)) | (off & 0xF));
        *reinterpret_cast<ushort_t*>(As + addr) = f2bf(acc);
    }

    __syncthreads();

    // Phase 2: MFMA GEMM (64 x 128, K=64)
    f32x4 acc[2][4];
#pragma unroll
    for (int i = 0; i < 2; ++i)
#pragma unroll
        for (int j = 0; j < 4; ++j) acc[i][j] = f32x4{0.f, 0.f, 0.f, 0.f};

#pragma unroll
    for (int ks = 0; ks < 2; ++ks) {
        int boff = ks * 64 + kg * 16;
        int row0 = wm0 + lr;
        int row1 = wm0 + 16 + lr;
        short8 a0 = *reinterpret_cast<const short8*>(As + row0 * K2 + (boff ^ ((row0 & 7) << 4)));
        short8 a1 = *reinterpret_cast<const short8*>(As + row1 * K2 + (boff ^ ((row1 & 7) << 4)));
#pragma unroll
        for (int fn = 0; fn < 4; ++fn) {
            acc[0][fn] = __builtin_amdgcn_mfma_f32_16x16x32_bf16(a0, bfrag[ks][fn], acc[0][fn], 0, 0, 0);
            acc[1][fn] = __builtin_amdgcn_mfma_f32_16x16x32_bf16(a1, bfrag[ks][fn], acc[1][fn], 0, 0, 0);
        }
    }

    // Epilogue: relu + bf16 store + column stat partials
    float s_c[4] = {0.f, 0.f, 0.f, 0.f};
    float q_c[4] = {0.f, 0.f, 0.f, 0.f};
#pragma unroll
    for (int fm = 0; fm < 2; ++fm) {
        int rowb = r0 + wm0 + fm * 16 + kg * 4;
#pragma unroll
        for (int i = 0; i < 4; ++i) {
            int r = rowb + i;
            if (r < n) {
#pragma unroll
                for (int fn = 0; fn < 4; ++fn) {
                    float v = fmaxf(acc[fm][fn][i], 0.f);
                    s_c[fn] += v;
                    q_c[fn] += v * v;
                    int c = wn0 + fn * 16 + lr;
                    h1[(size_t)r * 128 + c] = f2bf(v);
                }
            }
        }
    }
#pragma unroll
    for (int fn = 0; fn < 4; ++fn) {
        float s = s_c[fn], q = q_c[fn];
        s += __shfl_xor(s, 16); q += __shfl_xor(q, 16);
        s += __shfl_xor(s, 32); q += __shfl_xor(q, 32);
        if (lane < 16) {
            int c = wn0 + fn * 16 + lane;
            atomicAdd(&lsum[c], s);
            atomicAdd(&lsq[c], q);
        }
    }
    __syncthreads();
    if (tid < 128) {
        psum[(size_t)blockIdx.x * 128 + tid] = lsum[tid];
        psq [(size_t)blockIdx.x * 128 + tid] = lsq[tid];
    }
}

// ---------------- SpMM layer 2 (16 edges in flight) + inline BN1 fold ----------

__global__ void spmm2_k(const ushort_t* __restrict__ h1, const int* __restrict__ rp,
                        const unsigned int* __restrict__ ep,
                        const float* __restrict__ colsum1, const float* __restrict__ colsq1,
                        const float* __restrict__ gamma1, const float* __restrict__ beta1,
                        ushort_t* __restrict__ a2, int n) {
    int wid  = (blockIdx.x * blockDim.x + threadIdx.x) >> 6;
    int lane = threadIdx.x & 63;
    if (wid >= n) return;
    int beg = rp[wid], end = rp[wid + 1];
    float a0 = 0.f, a1 = 0.f, wacc = 0.f;
    int p = beg;
    for (; p + 16 <= end; p += 16) {
        unsigned int m[16];
#pragma unroll
        for (int j = 0; j < 16; ++j) m[j] = ep[p + j];
        unsigned int u[16];
#pragma unroll
        for (int j = 0; j < 16; ++j)
            u[j] = *reinterpret_cast<const unsigned int*>(
                h1 + (size_t)(m[j] & 0xffffu) * 128 + lane * 2);
#pragma unroll
        for (int j = 0; j < 16; ++j) {
            float wt = hi16_as_f(m[j]);
            wacc += wt;
            a0 = fmaf(wt, bf2f_u(u[j] & 0xffffu), a0);
            a1 = fmaf(wt, bf2f_u(u[j] >> 16), a1);
        }
    }
    for (; p + 4 <= end; p += 4) {
        unsigned int m[4];
#pragma unroll
        for (int j = 0; j < 4; ++j) m[j] = ep[p + j];
        unsigned int u[4];
#pragma unroll
        for (int j = 0; j < 4; ++j)
            u[j] = *reinterpret_cast<const unsigned int*>(
                h1 + (size_t)(m[j] & 0xffffu) * 128 + lane * 2);
#pragma unroll
        for (int j = 0; j < 4; ++j) {
            float wt = hi16_as_f(m[j]);
            wacc += wt;
            a0 = fmaf(wt, bf2f_u(u[j] & 0xffffu), a0);
            a1 = fmaf(wt, bf2f_u(u[j] >> 16), a1);
        }
    }
    for (; p < end; ++p) {
        unsigned int m = ep[p];
        float wt = hi16_as_f(m);
        wacc += wt;
        unsigned int u = *reinterpret_cast<const unsigned int*>(
            h1 + (size_t)(m & 0xffffu) * 128 + lane * 2);
        a0 = fmaf(wt, bf2f_u(u & 0xffffu), a0);
        a1 = fmaf(wt, bf2f_u(u >> 16), a1);
    }
    float2 cs = *reinterpret_cast<const float2*>(colsum1 + lane * 2);
    float2 cq = *reinterpret_cast<const float2*>(colsq1 + lane * 2);
    float2 g  = *reinterpret_cast<const float2*>(gamma1 + lane * 2);
    float2 be = *reinterpret_cast<const float2*>(beta1 + lane * 2);
    float m0 = cs.x * (1.0f / NN);
    float v0 = cq.x * (1.0f / NN) - m0 * m0;
    float sc0 = g.x * rsqrtf(v0 + 1e-5f);
    float bi0 = be.x - m0 * sc0;
    float m1 = cs.y * (1.0f / NN);
    float v1 = cq.y * (1.0f / NN) - m1 * m1;
    float sc1 = g.y * rsqrtf(v1 + 1e-5f);
    float bi1 = be.y - m1 * sc1;
    unsigned int o = (unsigned int)f2bf(fmaf(a0, sc0, wacc * bi0))
                   | ((unsigned int)f2bf(fmaf(a1, sc1, wacc * bi1)) << 16);
    *reinterpret_cast<unsigned int*>(a2 + (size_t)wid * 128 + lane * 2) = o;
}

// ---------------- MFMA GEMM layer 2 + per-block stat partials ----------------

template <int K>
__launch_bounds__(256, 4)
__global__ void mgemm_k(const ushort_t* __restrict__ A, const ushort_t* __restrict__ BT,
                        ushort_t* __restrict__ Cout, float* __restrict__ psum,
                        float* __restrict__ psq, int n, int N) {
    constexpr int K2 = K * 2;            // row bytes
    __shared__ char As[64 * K2];
    __shared__ float lsum[128], lsq[128];
    int tid = threadIdx.x;
    int r0  = blockIdx.x * 64;
    int c0  = blockIdx.y * 128;

    if (tid < 128) { lsum[tid] = 0.f; lsq[tid] = 0.f; }

    {
        const char* Ab = (const char*)(A + (size_t)r0 * K);
#pragma unroll
        for (int it = 0; it < (64 * K2) / 4096; ++it) {
            int p   = (it * 256 + tid) * 16;
            int row = p / K2;
            int cb  = p - row * K2;
            short8 v = *reinterpret_cast<const short8*>(Ab + p);
            *reinterpret_cast<short8*>(As + row * K2 + (cb ^ ((row & 7) << 4))) = v;
        }
    }

    int lane = tid & 63;
    int w    = tid >> 6;
    int wm0  = (w >> 1) * 32;
    int wn0  = (w & 1) * 64;
    int kg   = lane >> 4;
    int lr   = lane & 15;

    short8 bfrag[K / 32][4];
#pragma unroll
    for (int fn = 0; fn < 4; ++fn) {
        const ushort_t* bp = BT + (size_t)(c0 + wn0 + fn * 16 + lr) * K + kg * 8;
#pragma unroll
        for (int ks = 0; ks < K / 32; ++ks)
            bfrag[ks][fn] = *reinterpret_cast<const short8*>(bp + ks * 32);
    }

    __syncthreads();

    f32x4 acc[2][4];
#pragma unroll
    for (int i = 0; i < 2; ++i)
#pragma unroll
        for (int j = 0; j < 4; ++j) acc[i][j] = f32x4{0.f, 0.f, 0.f, 0.f};

#pragma unroll
    for (int ks = 0; ks < K / 32; ++ks) {
        int boff = ks * 64 + kg * 16;
        int row0 = wm0 + lr;
        int row1 = wm0 + 16 + lr;
        short8 a0 = *reinterpret_cast<const short8*>(As + row0 * K2 + (boff ^ ((row0 & 7) << 4)));
        short8 a1 = *reinterpret_cast<const short8*>(As + row1 * K2 + (boff ^ ((row1 & 7) << 4)));
#pragma unroll
        for (int fn = 0; fn < 4; ++fn) {
            acc[0][fn] = __builtin_amdgcn_mfma_f32_16x16x32_bf16(a0, bfrag[ks][fn], acc[0][fn], 0, 0, 0);
            acc[1][fn] = __builtin_amdgcn_mfma_f32_16x16x32_bf16(a1, bfrag[ks][fn], acc[1][fn], 0, 0, 0);
        }
    }

    float s_c[4] = {0.f, 0.f, 0.f, 0.f};
    float q_c[4] = {0.f, 0.f, 0.f, 0.f};
#pragma unroll
    for (int fm = 0; fm < 2; ++fm) {
        int rowb = r0 + wm0 + fm * 16 + kg * 4;
#pragma unroll
        for (int i = 0; i < 4; ++i) {
            int r = rowb + i;
            if (r < n) {
#pragma unroll
                for (int fn = 0; fn < 4; ++fn) {
                    float v = fmaxf(acc[fm][fn][i], 0.f);
                    s_c[fn] += v;
                    q_c[fn] += v * v;
                    int c = c0 + wn0 + fn * 16 + lr;
                    Cout[(size_t)r * N + c] = f2bf(v);
                }
            }
        }
    }
#pragma unroll
    for (int fn = 0; fn < 4; ++fn) {
        float s = s_c[fn], q = q_c[fn];
        s += __shfl_xor(s, 16); q += __shfl_xor(q, 16);
        s += __shfl_xor(s, 32); q += __shfl_xor(q, 32);
        if (lane < 16) {
            int c = wn0 + fn * 16 + lane;
            atomicAdd(&lsum[c], s);
            atomicAdd(&lsq[c], q);
        }
    }
    __syncthreads();
    if (tid < 128) {
        psum[(size_t)blockIdx.x * N + c0 + tid] = lsum[tid];
        psq [(size_t)blockIdx.x * N + c0 + tid] = lsq[tid];
    }
}

// ---------------- wide partial reduce -> colsum/colsq (64-deep atomic chains) -------

template <int F>
__global__ void red_k(const float* __restrict__ psum, const float* __restrict__ psq,
                      float* __restrict__ colsum, float* __restrict__ colsq, int nblk) {
    constexpr int RG = 256 / F;
    __shared__ float ls[256], lq[256];
    int tid = threadIdx.x;
    int c   = tid & (F - 1);
    int rg  = tid / F;
    float s = 0.f, q = 0.f;
    for (int b = blockIdx.x * RG + rg; b < nblk; b += gridDim.x * RG) {
        s += psum[(size_t)b * F + c];
        q += psq [(size_t)b * F + c];
    }
    ls[tid] = s; lq[tid] = q;
    __syncthreads();
    if (tid < F) {
#pragma unroll
        for (int g = 1; g < RG; ++g) { s += ls[g * F + tid]; q += lq[g * F + tid]; }
        atomicAdd(&colsum[tid], s);
        atomicAdd(&colsq[tid], q);
    }
}

// out[i] = h2(bf16) * scale[c] + bias[c]; BN2 finalize inline (octet is
// grid-stride-invariant -> 8 scale/bias pairs computed once into registers).
__global__ void norm_out_k(const ushort_t* __restrict__ h2, float* __restrict__ out,
                           const float* __restrict__ colsum2, const float* __restrict__ colsq2,
                           const float* __restrict__ gamma2, const float* __restrict__ beta2,
                           int n8) {
    int i = blockIdx.x * blockDim.x + threadIdx.x;
    int stride = gridDim.x * blockDim.x;
    int c = (i * 8) & 255;
    float4 s0, s1, b0, b1;
    {
        float sc[8], bi[8];
#pragma unroll
        for (int j = 0; j < 8; ++j) {
            float m = colsum2[c + j] * (1.0f / NN);
            float v = colsq2[c + j] * (1.0f / NN) - m * m;
            float s = gamma2[c + j] * rsqrtf(v + 1e-5f);
            sc[j] = s;
            bi[j] = beta2[c + j] - m * s;
        }
        s0 = float4{sc[0], sc[1], sc[2], sc[3]};
        s1 = float4{sc[4], sc[5], sc[6], sc[7]};
        b0 = float4{bi[0], bi[1], bi[2], bi[3]};
        b1 = float4{bi[4], bi[5], bi[6], bi[7]};
    }
    for (; i < n8; i += stride) {
        short8 v = reinterpret_cast<const short8*>(h2)[i];
        float4 o0, o1;
        o0.x = fmaf(bf2f((ushort_t)v[0]), s0.x, b0.x);
        o0.y = fmaf(bf2f((ushort_t)v[1]), s0.y, b0.y);
        o0.z = fmaf(bf2f((ushort_t)v[2]), s0.z, b0.z);
        o0.w = fmaf(bf2f((ushort_t)v[3]), s0.w, b0.w);
        o1.x = fmaf(bf2f((ushort_t)v[4]), s1.x, b1.x);
        o1.y = fmaf(bf2f((ushort_t)v[5]), s1.y, b1.y);
        o1.z = fmaf(bf2f((ushort_t)v[6]), s1.z, b1.z);
        o1.w = fmaf(bf2f((ushort_t)v[7]), s1.w, b1.w);
        reinterpret_cast<float4*>(out)[i * 2 + 0] = o0;
        reinterpret_cast<float4*>(out)[i * 2 + 1] = o1;
    }
}

// ---------------- launch ----------------

extern "C" void kernel_launch(void* const* d_in, const int* in_sizes, int n_in,
                              void* d_out, int out_size, void* d_ws, size_t ws_size,
                              hipStream_t stream) {
    const float* y      = (const float*)d_in[0];
    const int*   esrc   = (const int*)d_in[1];
    const int*   edst   = (const int*)d_in[2];
    const float* ew     = (const float*)d_in[3];
    const float* W1     = (const float*)d_in[4];
    const float* gamma1 = (const float*)d_in[5];
    const float* beta1  = (const float*)d_in[6];
    const float* W2     = (const float*)d_in[7];
    const float* gamma2 = (const float*)d_in[8];
    const float* beta2  = (const float*)d_in[9];
    float* out = (float*)d_out;

    char* ws = (char*)d_ws;
    size_t off = 0;
    auto alloc = [&](size_t bytes) -> void* {
        void* p = (void*)(ws + off);
        off += (bytes + 255) & ~(size_t)255;
        return p;
    };
    ushort_t* ybf  = (ushort_t*)alloc((size_t)NN * 64 * 2);
    ushort_t* h1   = (ushort_t*)alloc((size_t)NN * 128 * 2);
    ushort_t* a2   = (ushort_t*)alloc((size_t)NN * 128 * 2);
    ushort_t* h2   = (ushort_t*)alloc((size_t)NN * 256 * 2);
    ushort_t* w1t  = (ushort_t*)alloc(128 * 64 * 2);
    ushort_t* w2t  = (ushort_t*)alloc(256 * 128 * 2);
    int*   rp      = (int*)alloc((NN + 1) * 4);
    unsigned int* epack = (unsigned int*)alloc((size_t)NE * 4);
    uint2* tmp8    = (uint2*)alloc((size_t)NE * 8);
    int*   cnt     = (int*)alloc((size_t)NB * NBLK_E * 4);
    int*   btot    = (int*)alloc(NB * 4);
    float* psum1   = (float*)alloc((size_t)NBLK_M * 128 * 4);
    float* psq1    = (float*)alloc((size_t)NBLK_M * 128 * 4);
    float* psum2   = (float*)alloc((size_t)NBLK_M * 256 * 4);
    float* psq2    = (float*)alloc((size_t)NBLK_M * 256 * 4);
    float* stats   = (float*)alloc(768 * 4);   // colsum1[128] colsq1[128] colsum2[256] colsq2[256]
    float* colsum1 = stats;
    float* colsq1  = stats + 128;
    float* colsum2 = stats + 256;
    float* colsq2  = stats + 512;
    (void)alloc(64 * 1024);  // slack: gemm A-staging over-reads past row n (never stored)

    hipMemsetAsync(stats, 0, 768 * 4, stream);

    // fused conversions
    cvt_all_k<<<(NY4 + 128 * 64 + 256 * 128 + 255) / 256, 256, 0, stream>>>(
        y, W1, W2, ybf, w1t, w2t);

    // CSR build (by dst): block-local bucket sort -> bucket totals -> merge+scan+rp
    bblk_k<<<NBLK_E, 256, 0, stream>>>(esrc, edst, ew, tmp8, cnt, NE);
    bstat_k<<<NB, 256, 0, stream>>>(cnt, btot);
    bsort_k<<<NB, 256, 0, stream>>>(tmp8, cnt, btot, rp, epack, NN);

    // Layer 1 (fused): spmm + GEMM + stats partials in one kernel
    fused1_k<<<NBLK_M, 256, 0, stream>>>(ybf, rp, epack, w1t, h1, psum1, psq1, NN);
    red_k<128><<<64, 256, 0, stream>>>(psum1, psq1, colsum1, colsq1, NBLK_M);

    // Layer 2: a2 = BN1-folded spmm(h1) (inline scale/bias); h2 = relu(a2 @ W2) + stats
    spmm2_k<<<(NN + 3) / 4, 256, 0, stream>>>(h1, rp, epack, colsum1, colsq1,
                                              gamma1, beta1, a2, NN);
    mgemm_k<128><<<dim3(NBLK_M, 2), 256, 0, stream>>>(
        a2, w2t, h2, psum2, psq2, NN, 256);
    red_k<256><<<64, 256, 0, stream>>>(psum2, psq2, colsum2, colsq2, NBLK_M);

    // BN2 finalize fused into the normalize pass
    norm_out_k<<<2048, 256, 0, stream>>>(h2, out, colsum2, colsq2, gamma2, beta2,
                                         NN * 256 / 8);
}

// Round 12
// 154.275 us; speedup vs baseline: 1.2709x; 1.2709x over previous
//
#include <hip/hip_runtime.h>

#define NN 50000
#define NE 800000

typedef unsigned short ushort_t;
typedef __attribute__((ext_vector_type(8))) short short8;
typedef __attribute__((ext_vector_type(4))) float f32x4;

constexpr int NB   = (NN + 127) / 128;                        // 391 dst-buckets (128 nodes)
constexpr int BCAP = 4096;                                    // bucket capacity (avg 2048)
constexpr int CH     = 1024;                                  // edges per phase-A block
constexpr int NBLK_E = (NE + CH - 1) / CH;                    // 782
constexpr int NBLK_M = (NN + 63) / 64;                        // 782 GEMM row-blocks
constexpr int NY4    = NN * 64 / 4;                           // 800000 float4 groups of y
constexpr int CVT_N  = NY4 + 128 * 64 + 256 * 128 + 768;      // cvt grid size (+stats zero)

// ---------------- bf16 helpers (bit-exact, RNE) ----------------
__device__ __forceinline__ float bf2f(ushort_t u) {
    union { unsigned int i; float f; } v;
    v.i = ((unsigned int)u) << 16;
    return v.f;
}
__device__ __forceinline__ float bf2f_u(unsigned int lo16) {  // low 16 bits hold bf16
    union { unsigned int i; float f; } v;
    v.i = lo16 << 16;
    return v.f;
}
__device__ __forceinline__ float hi16_as_f(unsigned int u) {  // high 16 bits hold bf16
    union { unsigned int i; float f; } v;
    v.i = u & 0xffff0000u;
    return v.f;
}
__device__ __forceinline__ ushort_t f2bf(float f) {
    union { float f; unsigned int u; } v;
    v.f = f;
    unsigned int r = (v.u + 0x7fffu + ((v.u >> 16) & 1u)) >> 16;
    return (ushort_t)r;
}

// ------------- fused conversions (y -> bf16, W1^T, W2^T) + stats zero -------------

__global__ void cvt_all_k(const float* __restrict__ y, const float* __restrict__ W1,
                          const float* __restrict__ W2, ushort_t* __restrict__ ybf,
                          ushort_t* __restrict__ w1t, ushort_t* __restrict__ w2t,
                          float* __restrict__ stats) {
    int i = blockIdx.x * blockDim.x + threadIdx.x;
    if (i < NY4) {
        float4 v = reinterpret_cast<const float4*>(y)[i];
        ushort4 o;
        o.x = f2bf(v.x); o.y = f2bf(v.y); o.z = f2bf(v.z); o.w = f2bf(v.w);
        reinterpret_cast<ushort4*>(ybf)[i] = o;
    } else if (i < NY4 + 128 * 64) {
        int j = i - NY4;                  // w1t[c][k] = bf(W1[k][c]), W1 is [64][128]
        int c = j >> 6, k = j & 63;
        w1t[j] = f2bf(W1[k * 128 + c]);
    } else if (i < NY4 + 128 * 64 + 256 * 128) {
        int j = i - NY4 - 128 * 64;       // w2t[c][k] = bf(W2[k][c]), W2 is [128][256]
        int c = j >> 7, k = j & 127;
        w2t[j] = f2bf(W2[k * 256 + c]);
    } else if (i < CVT_N) {
        stats[i - (NY4 + 128 * 64 + 256 * 128)] = 0.f;
    }
}

// ---------------- CSR reorder, atomic-free at global scope ----------------
// Phase A: per-block LDS bucket sort of a 1024-edge chunk (782 blocks for TLP);
// coalesced block-major write of bucketed records + (cnt<<16|lofs) table.
// rec: .x = src | (dst&127)<<16 ; .y = w_bf16<<16

__global__ void bblk_k(const int* __restrict__ src, const int* __restrict__ dst,
                       const float* __restrict__ w, uint2* __restrict__ tmp,
                       int* __restrict__ cnt, int E) {
    __shared__ int lcnt[NB], lcur[NB];
    __shared__ int sm[256];
    __shared__ uint2 rec[CH];
    int b = blockIdx.x, tid = threadIdx.x;
    int e0 = b * CH;
    int ec = min(CH, E - e0);
    for (int i = tid; i < NB; i += 256) lcnt[i] = 0;
    __syncthreads();
    for (int i = tid; i < ec; i += 256)
        atomicAdd(&lcnt[dst[e0 + i] >> 7], 1);
    __syncthreads();
    // parallel exclusive scan of lcnt -> lcur (2 entries/thread)
    {
        int i0 = tid * 2;
        int v0 = (i0 < NB) ? lcnt[i0] : 0;
        int v1 = (i0 + 1 < NB) ? lcnt[i0 + 1] : 0;
        int s = v0 + v1;
        sm[tid] = s;
        __syncthreads();
        for (int off = 1; off < 256; off <<= 1) {
            int x = (tid >= off) ? sm[tid - off] : 0;
            __syncthreads();
            sm[tid] += x;
            __syncthreads();
        }
        int excl = sm[tid] - s;
        if (i0 < NB) lcur[i0] = excl;
        if (i0 + 1 < NB) lcur[i0 + 1] = excl + v0;
    }
    __syncthreads();
    for (int q = tid; q < NB; q += 256)
        cnt[q * NBLK_E + b] = (lcnt[q] << 16) | lcur[q];
    __syncthreads();
    for (int i = tid; i < ec; i += 256) {
        int d = dst[e0 + i];
        int p = atomicAdd(&lcur[d >> 7], 1);
        uint2 r;
        r.x = (unsigned int)src[e0 + i] | ((unsigned int)(d & 127) << 16);
        r.y = ((unsigned int)f2bf(w[e0 + i])) << 16;
        rec[p] = r;
    }
    __syncthreads();
    for (int i = tid; i < ec; i += 256)
        tmp[(size_t)e0 + i] = rec[i];
}

// per-bucket totals from cnt table (coalesced row reduce, 782 entries/row)
__global__ void bstat_k(const int* __restrict__ cnt, int* __restrict__ btot) {
    __shared__ int red[256];
    int q = blockIdx.x, tid = threadIdx.x;
    int s = 0;
    for (int b = tid; b < NBLK_E; b += 256) s += cnt[q * NBLK_E + b] >> 16;
    red[tid] = s;
    __syncthreads();
    for (int off = 128; off > 0; off >>= 1) {
        if (tid < off) red[tid] += red[tid + off];
        __syncthreads();
    }
    if (tid == 0) btot[q] = red[0];
}

// Phase B: one block per bucket — computes its own bucket start (prefix of btot),
// gathers the 782 runs, LDS counting-sort by dst&127, writes final CSR-ordered
// epack coalesced + per-node rp.
__global__ void bsort_k(const uint2* __restrict__ tmp, const int* __restrict__ cnt,
                        const int* __restrict__ btot, int* __restrict__ rp,
                        unsigned int* __restrict__ epack, int n) {
    __shared__ int rstart[NBLK_E + 1], rlofs[NBLK_E], rcnt[NBLK_E];
    __shared__ int c128[128], cur128[128], ex128[128];
    __shared__ int pre[256];
    __shared__ int s_start;
    __shared__ uint2 rec8[BCAP];
    __shared__ unsigned int spk[BCAP];
    int q = blockIdx.x, tid = threadIdx.x;
    int d0 = q * 128;
    // load run counts/offsets for this bucket
    for (int b = tid; b < NBLK_E; b += 256) {
        int v = cnt[q * NBLK_E + b];
        rcnt[b]  = v >> 16;
        rlofs[b] = v & 0xffff;
    }
    if (tid < 128) c128[tid] = 0;
    // bucket start = sum btot[0..q)
    {
        int part = 0;
        for (int b = tid; b < q; b += 256) part += btot[b];
        pre[tid] = part;
        __syncthreads();
        for (int off = 128; off > 0; off >>= 1) {
            if (tid < off) pre[tid] += pre[tid + off];
            __syncthreads();
        }
        if (tid == 0) {
            s_start = pre[0];
            if (q == 0) rp[n] = NE;
        }
        __syncthreads();
    }
    int start = s_start;
    // parallel exclusive scan of rcnt -> rstart (4 entries/thread)
    {
        int b0 = tid * 4;
        int w0 = (b0 + 0 < NBLK_E) ? rcnt[b0 + 0] : 0;
        int w1 = (b0 + 1 < NBLK_E) ? rcnt[b0 + 1] : 0;
        int w2 = (b0 + 2 < NBLK_E) ? rcnt[b0 + 2] : 0;
        int w3 = (b0 + 3 < NBLK_E) ? rcnt[b0 + 3] : 0;
        int s = w0 + w1 + w2 + w3;
        pre[tid] = s;
        __syncthreads();
        for (int off = 1; off < 256; off <<= 1) {
            int x = (tid >= off) ? pre[tid - off] : 0;
            __syncthreads();
            pre[tid] += x;
            __syncthreads();
        }
        int excl = pre[tid] - s;
        if (b0 + 0 < NBLK_E) rstart[b0 + 0] = excl;
        if (b0 + 1 < NBLK_E) rstart[b0 + 1] = excl + w0;
        if (b0 + 2 < NBLK_E) rstart[b0 + 2] = excl + w0 + w1;
        if (b0 + 3 < NBLK_E) rstart[b0 + 3] = excl + w0 + w1 + w2;
        if (tid == 255) rstart[NBLK_E] = pre[255];
    }
    __syncthreads();
    int total = min(rstart[NBLK_E], BCAP);
    for (int i = tid; i < total; i += 256) {
        int lo = 0, hi = NBLK_E;           // rstart[lo] <= i < rstart[hi]
        while (hi - lo > 1) {
            int mid = (lo + hi) >> 1;
            if (rstart[mid] <= i) lo = mid; else hi = mid;
        }
        uint2 r = tmp[(size_t)lo * CH + rlofs[lo] + (i - rstart[lo])];
        rec8[i] = r;
        atomicAdd(&c128[(r.x >> 16) & 127], 1);
    }
    __syncthreads();
    if (tid == 0) {
        int run = 0;
        for (int d = 0; d < 128; ++d) { ex128[d] = run; cur128[d] = run; run += c128[d]; }
    }
    __syncthreads();
    if (tid < 128 && d0 + tid < n) rp[d0 + tid] = start + ex128[tid];
    for (int i = tid; i < total; i += 256) {
        uint2 r = rec8[i];
        int p = atomicAdd(&cur128[(r.x >> 16) & 127], 1);
        spk[p] = r.y | (r.x & 0xffffu);
    }
    __syncthreads();
    for (int i = tid; i < total; i += 256)
        epack[start + i] = spk[i];
}

// ---------------- SpMM (bf16 gather, one wave per node, 16 edges in flight) --------

__global__ void spmm1_k(const ushort_t* __restrict__ yb, const int* __restrict__ rp,
                        const unsigned int* __restrict__ ep,
                        ushort_t* __restrict__ t1, int n) {
    int wid  = (blockIdx.x * blockDim.x + threadIdx.x) >> 6;
    int lane = threadIdx.x & 63;
    if (wid >= n) return;
    int beg = rp[wid], end = rp[wid + 1];
    float acc = 0.f;
    int p = beg;
    for (; p + 16 <= end; p += 16) {
        unsigned int m[16];
#pragma unroll
        for (int j = 0; j < 16; ++j) m[j] = ep[p + j];
        ushort_t u[16];
#pragma unroll
        for (int j = 0; j < 16; ++j)
            u[j] = yb[(size_t)(m[j] & 0xffffu) * 64 + lane];
#pragma unroll
        for (int j = 0; j < 16; ++j)
            acc = fmaf(hi16_as_f(m[j]), bf2f(u[j]), acc);
    }
    for (; p + 4 <= end; p += 4) {
        unsigned int m[4];
#pragma unroll
        for (int j = 0; j < 4; ++j) m[j] = ep[p + j];
        ushort_t u[4];
#pragma unroll
        for (int j = 0; j < 4; ++j)
            u[j] = yb[(size_t)(m[j] & 0xffffu) * 64 + lane];
#pragma unroll
        for (int j = 0; j < 4; ++j)
            acc = fmaf(hi16_as_f(m[j]), bf2f(u[j]), acc);
    }
    for (; p < end; ++p) {
        unsigned int m = ep[p];
        acc = fmaf(hi16_as_f(m), bf2f(yb[(size_t)(m & 0xffffu) * 64 + lane]), acc);
    }
    t1[(size_t)wid * 64 + lane] = f2bf(acc);
}

// gather h1 (bf16, 128 cols, 2/lane); BN1 scale/bias computed INLINE from raw
// colsum1/colsq1 (bit-identical to a separate finalize): a2 = acc*sc + wsum*bi
__global__ void spmm2_k(const ushort_t* __restrict__ h1, const int* __restrict__ rp,
                        const unsigned int* __restrict__ ep,
                        const float* __restrict__ colsum1, const float* __restrict__ colsq1,
                        const float* __restrict__ gamma1, const float* __restrict__ beta1,
                        ushort_t* __restrict__ a2, int n) {
    int wid  = (blockIdx.x * blockDim.x + threadIdx.x) >> 6;
    int lane = threadIdx.x & 63;
    if (wid >= n) return;
    int beg = rp[wid], end = rp[wid + 1];
    float a0 = 0.f, a1 = 0.f, wacc = 0.f;
    int p = beg;
    for (; p + 16 <= end; p += 16) {
        unsigned int m[16];
#pragma unroll
        for (int j = 0; j < 16; ++j) m[j] = ep[p + j];
        unsigned int u[16];
#pragma unroll
        for (int j = 0; j < 16; ++j)
            u[j] = *reinterpret_cast<const unsigned int*>(
                h1 + (size_t)(m[j] & 0xffffu) * 128 + lane * 2);
#pragma unroll
        for (int j = 0; j < 16; ++j) {
            float wt = hi16_as_f(m[j]);
            wacc += wt;
            a0 = fmaf(wt, bf2f_u(u[j] & 0xffffu), a0);
            a1 = fmaf(wt, bf2f_u(u[j] >> 16), a1);
        }
    }
    for (; p + 4 <= end; p += 4) {
        unsigned int m[4];
#pragma unroll
        for (int j = 0; j < 4; ++j) m[j] = ep[p + j];
        unsigned int u[4];
#pragma unroll
        for (int j = 0; j < 4; ++j)
            u[j] = *reinterpret_cast<const unsigned int*>(
                h1 + (size_t)(m[j] & 0xffffu) * 128 + lane * 2);
#pragma unroll
        for (int j = 0; j < 4; ++j) {
            float wt = hi16_as_f(m[j]);
            wacc += wt;
            a0 = fmaf(wt, bf2f_u(u[j] & 0xffffu), a0);
            a1 = fmaf(wt, bf2f_u(u[j] >> 16), a1);
        }
    }
    for (; p < end; ++p) {
        unsigned int m = ep[p];
        float wt = hi16_as_f(m);
        wacc += wt;
        unsigned int u = *reinterpret_cast<const unsigned int*>(
            h1 + (size_t)(m & 0xffffu) * 128 + lane * 2);
        a0 = fmaf(wt, bf2f_u(u & 0xffffu), a0);
        a1 = fmaf(wt, bf2f_u(u >> 16), a1);
    }
    float2 cs = *reinterpret_cast<const float2*>(colsum1 + lane * 2);
    float2 cq = *reinterpret_cast<const float2*>(colsq1 + lane * 2);
    float2 g  = *reinterpret_cast<const float2*>(gamma1 + lane * 2);
    float2 be = *reinterpret_cast<const float2*>(beta1 + lane * 2);
    float m0 = cs.x * (1.0f / NN);
    float v0 = cq.x * (1.0f / NN) - m0 * m0;
    float sc0 = g.x * rsqrtf(v0 + 1e-5f);
    float bi0 = be.x - m0 * sc0;
    float m1 = cs.y * (1.0f / NN);
    float v1 = cq.y * (1.0f / NN) - m1 * m1;
    float sc1 = g.y * rsqrtf(v1 + 1e-5f);
    float bi1 = be.y - m1 * sc1;
    unsigned int o = (unsigned int)f2bf(fmaf(a0, sc0, wacc * bi0))
                   | ((unsigned int)f2bf(fmaf(a1, sc1, wacc * bi1)) << 16);
    *reinterpret_cast<unsigned int*>(a2 + (size_t)wid * 128 + lane * 2) = o;
}

// ---------------- MFMA GEMM + per-block stat partials (NO global atomics) ----------
// C[n x N] = relu( A[n x K](bf16) @ BT[N x K](bf16)^T ). Column sum/sum-sq partials
// go to pblk[blockIdx.x][c] non-atomic & coalesced; red_k reduces them later.
// Block: 4 waves (2x2), tile 64 x 128. A staged in LDS with XOR swizzle
// byte^=(row&7)<<4 (guide §6 G4).

template <int K>
__launch_bounds__(256, 4)
__global__ void mgemm_k(const ushort_t* __restrict__ A, const ushort_t* __restrict__ BT,
                        ushort_t* __restrict__ Cout, float* __restrict__ psum,
                        float* __restrict__ psq, int n, int N) {
    constexpr int K2 = K * 2;            // row bytes
    __shared__ char As[64 * K2];
    __shared__ float lsum[128], lsq[128];
    int tid = threadIdx.x;
    int r0  = blockIdx.x * 64;
    int c0  = blockIdx.y * 128;

    if (tid < 128) { lsum[tid] = 0.f; lsq[tid] = 0.f; }

    {
        const char* Ab = (const char*)(A + (size_t)r0 * K);
#pragma unroll
        for (int it = 0; it < (64 * K2) / 4096; ++it) {
            int p   = (it * 256 + tid) * 16;
            int row = p / K2;
            int cb  = p - row * K2;
            short8 v = *reinterpret_cast<const short8*>(Ab + p);
            *reinterpret_cast<short8*>(As + row * K2 + (cb ^ ((row & 7) << 4))) = v;
        }
    }

    int lane = tid & 63;
    int w    = tid >> 6;
    int wm0  = (w >> 1) * 32;
    int wn0  = (w & 1) * 64;
    int kg   = lane >> 4;
    int lr   = lane & 15;

    short8 bfrag[K / 32][4];
#pragma unroll
    for (int fn = 0; fn < 4; ++fn) {
        const ushort_t* bp = BT + (size_t)(c0 + wn0 + fn * 16 + lr) * K + kg * 8;
#pragma unroll
        for (int ks = 0; ks < K / 32; ++ks)
            bfrag[ks][fn] = *reinterpret_cast<const short8*>(bp + ks * 32);
    }

    __syncthreads();

    f32x4 acc[2][4];
#pragma unroll
    for (int i = 0; i < 2; ++i)
#pragma unroll
        for (int j = 0; j < 4; ++j) acc[i][j] = f32x4{0.f, 0.f, 0.f, 0.f};

#pragma unroll
    for (int ks = 0; ks < K / 32; ++ks) {
        int boff = ks * 64 + kg * 16;
        int row0 = wm0 + lr;
        int row1 = wm0 + 16 + lr;
        short8 a0 = *reinterpret_cast<const short8*>(As + row0 * K2 + (boff ^ ((row0 & 7) << 4)));
        short8 a1 = *reinterpret_cast<const short8*>(As + row1 * K2 + (boff ^ ((row1 & 7) << 4)));
#pragma unroll
        for (int fn = 0; fn < 4; ++fn) {
            acc[0][fn] = __builtin_amdgcn_mfma_f32_16x16x32_bf16(a0, bfrag[ks][fn], acc[0][fn], 0, 0, 0);
            acc[1][fn] = __builtin_amdgcn_mfma_f32_16x16x32_bf16(a1, bfrag[ks][fn], acc[1][fn], 0, 0, 0);
        }
    }

    float s_c[4] = {0.f, 0.f, 0.f, 0.f};
    float q_c[4] = {0.f, 0.f, 0.f, 0.f};
#pragma unroll
    for (int fm = 0; fm < 2; ++fm) {
        int rowb = r0 + wm0 + fm * 16 + kg * 4;
#pragma unroll
        for (int i = 0; i < 4; ++i) {
            int r = rowb + i;
            if (r < n) {
#pragma unroll
                for (int fn = 0; fn < 4; ++fn) {
                    float v = fmaxf(acc[fm][fn][i], 0.f);
                    s_c[fn] += v;
                    q_c[fn] += v * v;
                    int c = c0 + wn0 + fn * 16 + lr;
                    Cout[(size_t)r * N + c] = f2bf(v);
                }
            }
        }
    }
#pragma unroll
    for (int fn = 0; fn < 4; ++fn) {
        float s = s_c[fn], q = q_c[fn];
        s += __shfl_xor(s, 16); q += __shfl_xor(q, 16);
        s += __shfl_xor(s, 32); q += __shfl_xor(q, 32);
        if (lane < 16) {
            int c = wn0 + fn * 16 + lane;
            atomicAdd(&lsum[c], s);
            atomicAdd(&lsq[c], q);
        }
    }
    __syncthreads();
    if (tid < 128) {
        psum[(size_t)blockIdx.x * N + c0 + tid] = lsum[tid];
        psq [(size_t)blockIdx.x * N + c0 + tid] = lsq[tid];
    }
}

// ---------------- wide partial reduce -> colsum/colsq (64-deep atomic chains) -------

template <int F>
__global__ void red_k(const float* __restrict__ psum, const float* __restrict__ psq,
                      float* __restrict__ colsum, float* __restrict__ colsq, int nblk) {
    constexpr int RG = 256 / F;
    __shared__ float ls[256], lq[256];
    int tid = threadIdx.x;
    int c   = tid & (F - 1);
    int rg  = tid / F;
    float s = 0.f, q = 0.f;
    for (int b = blockIdx.x * RG + rg; b < nblk; b += gridDim.x * RG) {
        s += psum[(size_t)b * F + c];
        q += psq [(size_t)b * F + c];
    }
    ls[tid] = s; lq[tid] = q;
    __syncthreads();
    if (tid < F) {
#pragma unroll
        for (int g = 1; g < RG; ++g) { s += ls[g * F + tid]; q += lq[g * F + tid]; }
        atomicAdd(&colsum[tid], s);
        atomicAdd(&colsq[tid], q);
    }
}

// out[i] = h2(bf16) * scale[c] + bias[c]; BN2 finalize inline (octet is
// grid-stride-invariant -> 8 scale/bias pairs computed once into registers).
__global__ void norm_out_k(const ushort_t* __restrict__ h2, float* __restrict__ out,
                           const float* __restrict__ colsum2, const float* __restrict__ colsq2,
                           const float* __restrict__ gamma2, const float* __restrict__ beta2,
                           int n8) {
    int i = blockIdx.x * blockDim.x + threadIdx.x;
    int stride = gridDim.x * blockDim.x;
    int c = (i * 8) & 255;
    float4 s0, s1, b0, b1;
    {
        float sc[8], bi[8];
#pragma unroll
        for (int j = 0; j < 8; ++j) {
            float m = colsum2[c + j] * (1.0f / NN);
            float v = colsq2[c + j] * (1.0f / NN) - m * m;
            float s = gamma2[c + j] * rsqrtf(v + 1e-5f);
            sc[j] = s;
            bi[j] = beta2[c + j] - m * s;
        }
        s0 = float4{sc[0], sc[1], sc[2], sc[3]};
        s1 = float4{sc[4], sc[5], sc[6], sc[7]};
        b0 = float4{bi[0], bi[1], bi[2], bi[3]};
        b1 = float4{bi[4], bi[5], bi[6], bi[7]};
    }
    for (; i < n8; i += stride) {
        short8 v = reinterpret_cast<const short8*>(h2)[i];
        float4 o0, o1;
        o0.x = fmaf(bf2f((ushort_t)v[0]), s0.x, b0.x);
        o0.y = fmaf(bf2f((ushort_t)v[1]), s0.y, b0.y);
        o0.z = fmaf(bf2f((ushort_t)v[2]), s0.z, b0.z);
        o0.w = fmaf(bf2f((ushort_t)v[3]), s0.w, b0.w);
        o1.x = fmaf(bf2f((ushort_t)v[4]), s1.x, b1.x);
        o1.y = fmaf(bf2f((ushort_t)v[5]), s1.y, b1.y);
        o1.z = fmaf(bf2f((ushort_t)v[6]), s1.z, b1.z);
        o1.w = fmaf(bf2f((ushort_t)v[7]), s1.w, b1.w);
        reinterpret_cast<float4*>(out)[i * 2 + 0] = o0;
        reinterpret_cast<float4*>(out)[i * 2 + 1] = o1;
    }
}

// ---------------- launch ----------------

extern "C" void kernel_launch(void* const* d_in, const int* in_sizes, int n_in,
                              void* d_out, int out_size, void* d_ws, size_t ws_size,
                              hipStream_t stream) {
    const float* y      = (const float*)d_in[0];
    const int*   esrc   = (const int*)d_in[1];
    const int*   edst   = (const int*)d_in[2];
    const float* ew     = (const float*)d_in[3];
    const float* W1     = (const float*)d_in[4];
    const float* gamma1 = (const float*)d_in[5];
    const float* beta1  = (const float*)d_in[6];
    const float* W2     = (const float*)d_in[7];
    const float* gamma2 = (const float*)d_in[8];
    const float* beta2  = (const float*)d_in[9];
    float* out = (float*)d_out;

    char* ws = (char*)d_ws;
    size_t off = 0;
    auto alloc = [&](size_t bytes) -> void* {
        void* p = (void*)(ws + off);
        off += (bytes + 255) & ~(size_t)255;
        return p;
    };
    ushort_t* ybf  = (ushort_t*)alloc((size_t)NN * 64 * 2);
    ushort_t* t1   = (ushort_t*)alloc((size_t)NN * 64 * 2);
    ushort_t* h1   = (ushort_t*)alloc((size_t)NN * 128 * 2);
    ushort_t* a2   = (ushort_t*)alloc((size_t)NN * 128 * 2);
    ushort_t* h2   = (ushort_t*)alloc((size_t)NN * 256 * 2);
    ushort_t* w1t  = (ushort_t*)alloc(128 * 64 * 2);
    ushort_t* w2t  = (ushort_t*)alloc(256 * 128 * 2);
    int*   rp      = (int*)alloc((NN + 1) * 4);
    unsigned int* epack = (unsigned int*)alloc((size_t)NE * 4);
    uint2* tmp8    = (uint2*)alloc((size_t)NE * 8);
    int*   cnt     = (int*)alloc((size_t)NB * NBLK_E * 4);
    int*   btot    = (int*)alloc(NB * 4);
    float* psum1   = (float*)alloc((size_t)NBLK_M * 128 * 4);
    float* psq1    = (float*)alloc((size_t)NBLK_M * 128 * 4);
    float* psum2   = (float*)alloc((size_t)NBLK_M * 256 * 4);
    float* psq2    = (float*)alloc((size_t)NBLK_M * 256 * 4);
    float* stats   = (float*)alloc(768 * 4);   // colsum1[128] colsq1[128] colsum2[256] colsq2[256]
    float* colsum1 = stats;
    float* colsq1  = stats + 128;
    float* colsum2 = stats + 256;
    float* colsq2  = stats + 512;
    (void)alloc(64 * 1024);  // slack: gemm A-staging over-reads past row n (never stored)

    // fused conversions + stats zeroing
    cvt_all_k<<<(CVT_N + 255) / 256, 256, 0, stream>>>(y, W1, W2, ybf, w1t, w2t, stats);

    // CSR build (by dst): block-local bucket sort -> bucket totals -> merge+scan+rp
    bblk_k<<<NBLK_E, 256, 0, stream>>>(esrc, edst, ew, tmp8, cnt, NE);
    bstat_k<<<NB, 256, 0, stream>>>(cnt, btot);
    bsort_k<<<NB, 256, 0, stream>>>(tmp8, cnt, btot, rp, epack, NN);

    // Layer 1: t1 = spmm(ybf); h1 = relu(t1 @ W1) bf16 + per-block stats
    spmm1_k<<<(NN + 3) / 4, 256, 0, stream>>>(ybf, rp, epack, t1, NN);
    mgemm_k<64><<<dim3(NBLK_M, 1), 256, 0, stream>>>(
        t1, w1t, h1, psum1, psq1, NN, 128);
    red_k<128><<<64, 256, 0, stream>>>(psum1, psq1, colsum1, colsq1, NBLK_M);

    // Layer 2: a2 = BN1-folded spmm(h1) (inline scale/bias); h2 = relu(a2 @ W2) + stats
    spmm2_k<<<(NN + 3) / 4, 256, 0, stream>>>(h1, rp, epack, colsum1, colsq1,
                                              gamma1, beta1, a2, NN);
    mgemm_k<128><<<dim3(NBLK_M, 2), 256, 0, stream>>>(
        a2, w2t, h2, psum2, psq2, NN, 256);
    red_k<256><<<64, 256, 0, stream>>>(psum2, psq2, colsum2, colsq2, NBLK_M);

    // BN2 finalize fused into the normalize pass
    norm_out_k<<<2048, 256, 0, stream>>>(h2, out, colsum2, colsq2, gamma2, beta2,
                                         NN * 256 / 8);
}